// Round 9
// baseline (630.708 us; speedup 1.0000x reference)
//
#include <hip/hip_runtime.h>
#include <math.h>

#define N_ATOMS 20000
#define M 12
#define B 41
#define ORIG 92
#define F 64
#define D 169        // 2F + B
#define NCONV 3
#define K 3
#define TWOK 6
#define H 128
#define N0 400
#define EPS 1e-5f
#define KB (K * B)   // 123
#define NBRS 42      // packed nbr row stride (41 data + 1 zero pad for uint2)

// geometry
#define PQW 1024                 // PQ row width: [0,512)=P, [512,1024)=Q
#define LFRAG_PQ 65536           // ushorts per (layer,img): 2s x 64c16 x 64lane x 8e
#define LFRAG_BD 32768           // ushorts per (layer,img): 2s x 32c16 x 64lane x 8e
#define ATOMS_PER_BLK 4
#define ROWS 64                  // 4 atoms x 16 rows
#define THREADS 512
#define GRID (N_ATOMS / ATOMS_PER_BLK)   // 5000

typedef __attribute__((ext_vector_type(8))) short bf16x8;
typedef __attribute__((ext_vector_type(4))) float f32x4;

__device__ inline unsigned short f32_to_bf16(float v) {
    unsigned int x = __float_as_uint(v);
    unsigned int r = (x + 0x7fffu + ((x >> 16) & 1u)) >> 16;
    return (unsigned short)r;
}
__device__ inline float bf16_to_f32(unsigned short u) {
    return __uint_as_float(((unsigned int)u) << 16);
}
__device__ inline unsigned int pack_hilo(float v) {
    unsigned short hi = f32_to_bf16(v);
    unsigned short lo = f32_to_bf16(v - bf16_to_f32(hi));
    return (unsigned int)hi | ((unsigned int)lo << 16);
}
__device__ inline float unpack_hilo(unsigned int p) {
    return bf16_to_f32((unsigned short)(p & 0xFFFFu)) +
           bf16_to_f32((unsigned short)(p >> 16));
}

// padded col-space c in [0,512) -> W column; row = W row (must be < D)
__device__ inline float wlookup(const float* __restrict__ fc_w,
                                int layer, int row, int c) {
    int b3 = c >> 7, cc = c & 127;
    if (b3 < 3) return fc_w[((size_t)(layer * K + b3) * D + row) * D + cc];
    if (cc < KB) {
        int kk = cc / B, bb = cc - kk * B;
        return fc_w[((size_t)(layer * K + kk) * D + row) * D + 2 * F + bb];
    }
    return 0.f;
}

// ---------------- embedding: x = atom_fea @ emb_w + emb_b (f32 + packed) ---
__global__ void emb_kernel(const float* __restrict__ atom_fea,
                           const float* __restrict__ emb_w,
                           const float* __restrict__ emb_b,
                           float* __restrict__ x,
                           unsigned int* __restrict__ xp) {
    int i = blockIdx.x * blockDim.x + threadIdx.x;
    if (i >= N_ATOMS * F) return;
    int n = i / F, f = i % F;
    const float* a = atom_fea + n * ORIG;
    float acc = emb_b[f];
    #pragma unroll 4
    for (int d = 0; d < ORIG; ++d)
        acc = fmaf(a[d], emb_w[d * F + f], acc);
    x[i] = acc;
    xp[i] = pack_hilo(acc);
}

// ---------------- npack: nbr_fea f32 -> packed u32 rows of 42 -------------
__global__ void npack_kernel(const float* __restrict__ nbr_fea,
                             unsigned int* __restrict__ nbrp) {
    int i = blockIdx.x * blockDim.x + threadIdx.x;
    if (i >= N_ATOMS * M * NBRS) return;
    int nm = i / NBRS, slot = i - nm * NBRS;
    nbrp[i] = (slot < B) ? pack_hilo(nbr_fea[nm * B + slot]) : 0u;
}

// ------- prep_pq: W rows [0,128) -> bf16 hi/lo fragments for pq_kernel ----
// frag: [layer][img][s(2)][c16(64)][lane][e]; c16<32 = P (W rows 0..63),
// c16>=32 = Q (W rows 64..127); out col c = sub_c16*16 + (lane&15);
// W row = base + s*32 + (lane>>4)*8 + e
__global__ void prep_pq_kernel(const float* __restrict__ fc_w,
                               unsigned short* __restrict__ wtpq) {
    int i = blockIdx.x * blockDim.x + threadIdx.x;
    if (i >= NCONV * LFRAG_PQ) return;
    int layer = i / LFRAG_PQ;
    int r = i % LFRAG_PQ;
    int s = r / 32768;
    int r2 = r % 32768;
    int c16 = r2 / 512;
    int r3 = r2 % 512;
    int lane = r3 / 8, e = r3 % 8;
    int isQ = (c16 >= 32);
    int c = (isQ ? c16 - 32 : c16) * 16 + (lane & 15);
    int row = (isQ ? F : 0) + s * 32 + (lane >> 4) * 8 + e;   // < 128
    float v = wlookup(fc_w, layer, row, c);
    unsigned short hi = f32_to_bf16(v);
    unsigned short lo = f32_to_bf16(v - bf16_to_f32(hi));
    wtpq[(size_t)(layer * 2 + 0) * LFRAG_PQ + r] = hi;
    wtpq[(size_t)(layer * 2 + 1) * LFRAG_PQ + r] = lo;
}

// ------- prep_bond: W rows [128,169) -> fragments for conv (K=64 pad) -----
__global__ void prep_bond_kernel(const float* __restrict__ fc_w,
                                 unsigned short* __restrict__ wtb) {
    int i = blockIdx.x * blockDim.x + threadIdx.x;
    if (i >= NCONV * LFRAG_BD) return;
    int layer = i / LFRAG_BD;
    int r = i % LFRAG_BD;
    int s = r / 16384;
    int r2 = r % 16384;
    int c16 = r2 / 512;
    int r3 = r2 % 512;
    int lane = r3 / 8, e = r3 % 8;
    int c = c16 * 16 + (lane & 15);
    int row = 2 * F + s * 32 + (lane >> 4) * 8 + e;
    float v = (row < D) ? wlookup(fc_w, layer, row, c) : 0.f;
    unsigned short hi = f32_to_bf16(v);
    unsigned short lo = f32_to_bf16(v - bf16_to_f32(hi));
    wtb[(size_t)(layer * 2 + 0) * LFRAG_BD + r] = hi;
    wtb[(size_t)(layer * 2 + 1) * LFRAG_BD + r] = lo;
}

// ------- prep2: fold bn1(+fc bias) and bn2 into per-column scale/shift ----
__global__ void prep2_kernel(const float* __restrict__ fc_b,
                             const float* __restrict__ bn1_g,
                             const float* __restrict__ bn1_b,
                             const float* __restrict__ bn1_m,
                             const float* __restrict__ bn1_v,
                             const float* __restrict__ bn2_g,
                             const float* __restrict__ bn2_b,
                             const float* __restrict__ bn2_m,
                             const float* __restrict__ bn2_v,
                             float* __restrict__ sc1,
                             float* __restrict__ sh1,
                             float* __restrict__ sc2,
                             float* __restrict__ sh2) {
    int i = blockIdx.x * blockDim.x + threadIdx.x;
    if (i < NCONV * K * D) {
        float sc = bn1_g[i] * rsqrtf(bn1_v[i] + EPS);
        sc1[i] = sc;
        sh1[i] = fmaf(fc_b[i], sc, bn1_b[i] - bn1_m[i] * sc);
    }
    if (i < NCONV * K * F) {
        float sc = bn2_g[i] * rsqrtf(bn2_v[i] + EPS);
        sc2[i] = sc;
        sh2[i] = bn2_b[i] - bn2_m[i] * sc;
    }
}

// ---------------- pq_kernel: PQ = X @ [W_self | W_gath] ----------------
// block = 32 atoms, 8 waves; wave w owns c16 tiles w*8..w*8+7 of 64.
// A = 32 rows x 64 K, bf16 hi/lo in LDS, XOR swizzle (row&7)<<4.
__global__ __launch_bounds__(512, 4)
void pq_kernel(const unsigned int* __restrict__ xp,
               const unsigned short* __restrict__ wtl,
               float* __restrict__ pq) {
    __shared__ __align__(16) unsigned short s_a[2 * 32 * 64];  // 8 KB

    const int t = threadIdx.x;
    const int w = t >> 6, l = t & 63;
    const int l15 = l & 15, lane3 = l >> 4;
    const int n0 = blockIdx.x * 32;

    {   // stage: thread -> row t>>4, 2 uint2 pairs
        int row = t >> 4, j16 = t & 15;
        unsigned int mask = (unsigned int)((row & 7) << 4);
        char* hb = (char*)s_a + row * 128;
        const unsigned int* xr = xp + (n0 + row) * F;
        #pragma unroll
        for (int q = 0; q < 2; ++q) {
            int kp = j16 + 16 * q;
            uint2 u = *(const uint2*)&xr[kp * 2];
            unsigned int hip = (u.x & 0xFFFFu) | (u.y << 16);
            unsigned int lop = (u.x >> 16) | (u.y & 0xFFFF0000u);
            unsigned int byo = ((unsigned int)(kp * 4)) ^ mask;
            *(unsigned int*)(hb + byo) = hip;
            *(unsigned int*)(hb + byo + 4096) = lop;
        }
    }
    __syncthreads();

    f32x4 acc[2][8];
    #pragma unroll
    for (int a = 0; a < 2; ++a)
        #pragma unroll
        for (int tt = 0; tt < 8; ++tt)
            acc[a][tt] = (f32x4){0.f, 0.f, 0.f, 0.f};

    #pragma unroll
    for (int s = 0; s < 2; ++s) {
        bf16x8 ah[2], al[2];
        #pragma unroll
        for (int a = 0; a < 2; ++a) {
            int row = a * 16 + l15;
            int byte = row * 128 + ((s * 64 + lane3 * 16) ^ ((row & 7) << 4));
            ah[a] = *(const bf16x8*)((const char*)s_a + byte);
            al[a] = *(const bf16x8*)((const char*)s_a + byte + 4096);
        }
        #pragma unroll
        for (int tt = 0; tt < 8; ++tt) {
            const unsigned short* wp = wtl + s * 32768 + (w * 8 + tt) * 512 + l * 8;
            bf16x8 bh = *(const bf16x8*)wp;
            bf16x8 bl = *(const bf16x8*)(wp + LFRAG_PQ);
            #pragma unroll
            for (int a = 0; a < 2; ++a) {
                acc[a][tt] = __builtin_amdgcn_mfma_f32_16x16x32_bf16(ah[a], bh, acc[a][tt], 0, 0, 0);
                acc[a][tt] = __builtin_amdgcn_mfma_f32_16x16x32_bf16(ah[a], bl, acc[a][tt], 0, 0, 0);
                acc[a][tt] = __builtin_amdgcn_mfma_f32_16x16x32_bf16(al[a], bh, acc[a][tt], 0, 0, 0);
            }
        }
    }

    #pragma unroll
    for (int a = 0; a < 2; ++a)
        #pragma unroll
        for (int tt = 0; tt < 8; ++tt) {
            int col = (w * 8 + tt) * 16 + l15;
            int rowb = n0 + a * 16 + lane3 * 4;
            #pragma unroll
            for (int r = 0; r < 4; ++r)
                pq[(size_t)(rowb + r) * PQW + col] = acc[a][tt][r];
        }
}

// ---------------- conv: bond GEMM (K=64) + PQ gather-add + epilogue -------
// block = 4 atoms, 8 waves, tiles as before (w<6 gate, w>=6 bond).
// nbrp is updated IN PLACE (rows (n,m) touched only by atom n's block;
// all reads precede writes via barriers; npack refreshes it each launch).
template <bool NEED_NBR>
__global__ __launch_bounds__(THREADS, 4)
void conv_mfma(const float* __restrict__ xin,          // f32 residual
               unsigned int* __restrict__ nbrp,        // packed, in/out
               const int* __restrict__ idx,
               const unsigned short* __restrict__ wtl, // bond frags (layer)
               const float* __restrict__ pq,           // (N,1024)
               const float* __restrict__ sc1,
               const float* __restrict__ sh1,
               const float* __restrict__ sc2,
               const float* __restrict__ sh2,
               const float* __restrict__ atom_w,
               const float* __restrict__ atom_b,
               const float* __restrict__ nbr_w,
               const float* __restrict__ nbr_b,
               float* __restrict__ xout,
               unsigned int* __restrict__ xpout) {
    __shared__ __align__(16) char s_mem[24576];        // A imgs 16KB / s_nnk 23.6KB
    __shared__ float s_sum[ATOMS_PER_BLK * K * F];     // 3072 B
    __shared__ int s_idx[ATOMS_PER_BLK * M];           // 192 B

    const int t = threadIdx.x;
    const int w = t >> 6, l = t & 63;
    const int l15 = l & 15, lane3 = l >> 4;
    const int n0 = blockIdx.x * ATOMS_PER_BLK;

    if (t < ATOMS_PER_BLK * M) s_idx[t] = idx[n0 * M + t];

    {   // stage A: rows (a,m), 64 K-cols = nbr 41 + pad
        int srow = t >> 3, j8 = t & 7;
        int a = srow >> 4, m = srow & 15;
        unsigned int mask = (unsigned int)((srow & 7) << 4);
        char* hb = s_mem + srow * 128;
        if (m < M) {
            const unsigned int* nb = nbrp + (size_t)((n0 + a) * M + m) * NBRS;
            #pragma unroll
            for (int q = 0; q < 4; ++q) {
                int kp = j8 + 8 * q;
                uint2 u = (kp < 21) ? *(const uint2*)&nb[kp * 2]
                                    : make_uint2(0u, 0u);
                unsigned int hip = (u.x & 0xFFFFu) | (u.y << 16);
                unsigned int lop = (u.x >> 16) | (u.y & 0xFFFF0000u);
                unsigned int byo = ((unsigned int)(kp * 4)) ^ mask;
                *(unsigned int*)(hb + byo) = hip;
                *(unsigned int*)(hb + byo + 8192) = lop;
            }
        } else {
            #pragma unroll
            for (int q = 0; q < 4; ++q) {
                unsigned int byo = ((unsigned int)((j8 + 8 * q) * 4)) ^ mask;
                *(unsigned int*)(hb + byo) = 0u;
                *(unsigned int*)(hb + byo + 8192) = 0u;
            }
        }
    }
    __syncthreads();

    const int kk_gate = w >> 1, half = w & 1;
    int tile[4];
    if (w < 6) {
        tile[0] = kk_gate * 8 + half * 2 + 0;
        tile[1] = kk_gate * 8 + half * 2 + 1;
        tile[2] = tile[0] + 4;
        tile[3] = tile[1] + 4;
    } else {
        tile[0] = 24 + (w - 6) * 4 + 0;
        tile[1] = 24 + (w - 6) * 4 + 1;
        tile[2] = 24 + (w - 6) * 4 + 2;
        tile[3] = 24 + (w - 6) * 4 + 3;
    }

    f32x4 acc[ATOMS_PER_BLK][4];
    #pragma unroll
    for (int a = 0; a < ATOMS_PER_BLK; ++a)
        #pragma unroll
        for (int j = 0; j < 4; ++j)
            acc[a][j] = (f32x4){0.f, 0.f, 0.f, 0.f};

    if (!(w >= 6 && !NEED_NBR)) {
        #pragma unroll
        for (int s = 0; s < 2; ++s) {
            bf16x8 ah[ATOMS_PER_BLK], al[ATOMS_PER_BLK];
            #pragma unroll
            for (int a = 0; a < ATOMS_PER_BLK; ++a) {
                int row = a * 16 + l15;
                int byte = row * 128 + ((s * 64 + lane3 * 16) ^ ((row & 7) << 4));
                ah[a] = *(const bf16x8*)(s_mem + byte);
                al[a] = *(const bf16x8*)(s_mem + byte + 8192);
            }
            #pragma unroll
            for (int j = 0; j < 4; ++j) {
                const unsigned short* wp = wtl + s * 16384 + tile[j] * 512 + l * 8;
                bf16x8 bh = *(const bf16x8*)wp;
                bf16x8 bl = *(const bf16x8*)(wp + LFRAG_BD);
                #pragma unroll
                for (int a = 0; a < ATOMS_PER_BLK; ++a) {
                    acc[a][j] = __builtin_amdgcn_mfma_f32_16x16x32_bf16(ah[a], bh, acc[a][j], 0, 0, 0);
                    acc[a][j] = __builtin_amdgcn_mfma_f32_16x16x32_bf16(ah[a], bl, acc[a][j], 0, 0, 0);
                    acc[a][j] = __builtin_amdgcn_mfma_f32_16x16x32_bf16(al[a], bh, acc[a][j], 0, 0, 0);
                }
            }
        }
    }
    __syncthreads();   // s_a dead; bond waves overlay s_nnk

    float* s_nnk = (float*)s_mem;  // [4][3][12][41] f32 = 23616 B

    if (w < 6) {
        const int k = kk_gate;
        #pragma unroll
        for (int a = 0; a < ATOMS_PER_BLK; ++a) {
            const float* pqp = pq + (size_t)(n0 + a) * PQW;
            #pragma unroll
            for (int jp = 0; jp < 2; ++jp) {
                int colf = tile[jp] * 16 + l15;
                int colc = colf + 64;
                int e = (half * 2 + jp) * 16 + l15;
                int cf = k * D + e, cr = cf + F, c2 = k * F + e;
                float sc_f = sc1[cf], sh_f = sh1[cf];
                float sc_c = sc1[cr], sh_c = sh1[cr];
                float Pf = pqp[colf], Pc = pqp[colc];
                bool act = (lane3 < 3);
                float fv[4], cv[4];
                #pragma unroll
                for (int r = 0; r < 4; ++r) {
                    int mm = lane3 * 4 + r;
                    int qn = s_idx[a * M + (mm < M ? mm : 0)];
                    float Qf = pq[(size_t)qn * PQW + 512 + colf];
                    float Qc = pq[(size_t)qn * PQW + 512 + colc];
                    fv[r] = fmaf(acc[a][jp][r] + Pf + Qf, sc_f, sh_f);
                    cv[r] = fmaxf(fmaf(acc[a][jp + 2][r] + Pc + Qc, sc_c, sh_c), 0.f);
                }
                float mx = act ? fmaxf(fmaxf(fv[0], fv[1]), fmaxf(fv[2], fv[3])) : -1e30f;
                mx = fmaxf(mx, __shfl_xor(mx, 16));
                mx = fmaxf(mx, __shfl_xor(mx, 32));
                float se = 0.f, sp = 0.f;
                #pragma unroll
                for (int r = 0; r < 4; ++r) {
                    float ex = act ? __expf(fv[r] - mx) : 0.f;
                    se += ex;
                    sp = fmaf(ex, cv[r], sp);
                }
                se += __shfl_xor(se, 16);
                se += __shfl_xor(se, 32);
                sp += __shfl_xor(sp, 16);
                sp += __shfl_xor(sp, 32);
                float summed = sp / se;
                float outv = xin[(n0 + a) * F + e] + fmaf(summed, sc2[c2], sh2[c2]);
                if (lane3 == 0) s_sum[(a * K + k) * F + e] = outv;
            }
        }
    } else if (NEED_NBR) {
        #pragma unroll
        for (int a = 0; a < ATOMS_PER_BLK; ++a) {
            const float* pqp = pq + (size_t)(n0 + a) * PQW;
            #pragma unroll
            for (int j = 0; j < 4; ++j) {
                int cc = (w - 6) * 64 + j * 16 + l15;
                if (cc < KB) {
                    int kk = cc / B, bb = cc - kk * B;
                    int col = 384 + cc;
                    int scol = kk * D + 2 * F + bb;
                    float sc = sc1[scol], sh = sh1[scol];
                    float P1 = pqp[col];
                    #pragma unroll
                    for (int r = 0; r < 4; ++r) {
                        int mm = lane3 * 4 + r;
                        if (mm < M) {
                            int qn = s_idx[a * M + mm];
                            float Q1 = pq[(size_t)qn * PQW + 512 + col];
                            float nv = unpack_hilo(
                                nbrp[(size_t)((n0 + a) * M + mm) * NBRS + bb]);
                            s_nnk[((a * K + kk) * M + mm) * B + bb] =
                                fmaf(acc[a][j][r] + P1 + Q1, sc, sh) + nv;
                        }
                    }
                }
            }
        }
    }
    __syncthreads();

    // ---- atom gate: threads 0..255 = 4 atoms x 64 f ----
    if (t < ATOMS_PER_BLK * F) {
        int a2 = t >> 6, f = t & 63;
        float og[TWOK];
        #pragma unroll
        for (int j = 0; j < TWOK; ++j) {
            float v = atom_b[j];
            #pragma unroll
            for (int q = 0; q < K; ++q)
                v = fmaf(s_sum[(a2 * K + q) * F + f], atom_w[q * TWOK + j], v);
            og[j] = v;
        }
        float mx = fmaxf(fmaxf(og[K], og[K + 1]), og[K + 2]);
        float e0 = __expf(og[K] - mx), e1 = __expf(og[K + 1] - mx), e2 = __expf(og[K + 2] - mx);
        float inv = 1.f / (e0 + e1 + e2);
        float outv = (og[0] * e0 + og[1] * e1 + og[2] * e2) * inv;
        xout[(n0 + a2) * F + f] = outv;
        xpout[(n0 + a2) * F + f] = pack_hilo(outv);
    }

    // ---- bond gate: writes nbrp in place (slot 41 stays 0) ----
    if (NEED_NBR) {
        for (int i = t; i < ATOMS_PER_BLK * M * B; i += THREADS) {
            int a2 = i / (M * B);
            int r = i - a2 * (M * B);
            int m = r / B, b = r - m * B;
            float ng[TWOK];
            #pragma unroll
            for (int j = 0; j < TWOK; ++j) {
                float v = nbr_b[j];
                #pragma unroll
                for (int q = 0; q < K; ++q)
                    v = fmaf(s_nnk[((a2 * K + q) * M + m) * B + b], nbr_w[q * TWOK + j], v);
                ng[j] = v;
            }
            float mx = fmaxf(fmaxf(ng[K], ng[K + 1]), ng[K + 2]);
            float e0 = __expf(ng[K] - mx), e1 = __expf(ng[K + 1] - mx), e2 = __expf(ng[K + 2] - mx);
            float inv = 1.f / (e0 + e1 + e2);
            float v = (ng[0] * e0 + ng[1] * e1 + ng[2] * e2) * inv;
            nbrp[(size_t)((n0 + a2) * M + m) * NBRS + b] = pack_hilo(v);
        }
    }
}

// ---------------- pooling: segment sums via atomics ----------------
__global__ void pool_kernel(const float* __restrict__ x,
                            const int* __restrict__ cidx,
                            float* __restrict__ sums,
                            float* __restrict__ cnt) {
    int i = blockIdx.x * blockDim.x + threadIdx.x;
    if (i >= N_ATOMS * F) return;
    int n = i / F, f = i % F;
    int c = cidx[n];
    atomicAdd(&sums[c * F + f], x[i]);
    if (f == 0) atomicAdd(&cnt[c], 1.0f);
}

// ---------------- head: mean -> relu -> fc1 -> relu -> out ----------------
__global__ void head_kernel(const float* __restrict__ sums,
                            const float* __restrict__ cnt,
                            const float* __restrict__ fc1_w,
                            const float* __restrict__ fc1_b,
                            const float* __restrict__ out_w,
                            const float* __restrict__ out_b,
                            float* __restrict__ out) {
    const int c = blockIdx.x;
    const int t = threadIdx.x;  // 128 threads
    __shared__ float a[F];
    __shared__ float red[H];
    float inv_cnt = 1.f / fmaxf(cnt[c], 1.0f);
    if (t < F) a[t] = fmaxf(sums[c * F + t] * inv_cnt, 0.f);
    __syncthreads();
    float hv = fc1_b[t];
    #pragma unroll 4
    for (int f = 0; f < F; ++f)
        hv = fmaf(a[f], fc1_w[f * H + t], hv);
    hv = fmaxf(hv, 0.f);
    red[t] = hv * out_w[t];
    __syncthreads();
    for (int s = H / 2; s > 0; s >>= 1) {
        if (t < s) red[t] += red[t + s];
        __syncthreads();
    }
    if (t == 0) out[c] = red[0] + out_b[0];
}

extern "C" void kernel_launch(void* const* d_in, const int* in_sizes, int n_in,
                              void* d_out, int out_size, void* d_ws, size_t ws_size,
                              hipStream_t stream) {
    (void)in_sizes; (void)n_in; (void)out_size; (void)ws_size;
    const float* atom_fea = (const float*)d_in[0];
    const float* nbr_fea  = (const float*)d_in[1];
    const int*   nbr_idx  = (const int*)d_in[2];
    const int*   cidx     = (const int*)d_in[3];
    // d_in[4] = n_crystals (fixed 400)
    const float* emb_w = (const float*)d_in[5];
    const float* emb_b = (const float*)d_in[6];
    const float* fc_w  = (const float*)d_in[7];
    const float* fc_b  = (const float*)d_in[8];
    const float* bn1_g = (const float*)d_in[9];
    const float* bn1_b = (const float*)d_in[10];
    const float* bn1_m = (const float*)d_in[11];
    const float* bn1_v = (const float*)d_in[12];
    const float* bn2_g = (const float*)d_in[13];
    const float* bn2_b = (const float*)d_in[14];
    const float* bn2_m = (const float*)d_in[15];
    const float* bn2_v = (const float*)d_in[16];
    const float* atom_w = (const float*)d_in[17];
    const float* atom_b = (const float*)d_in[18];
    const float* nbr_w  = (const float*)d_in[19];
    const float* nbr_b  = (const float*)d_in[20];
    const float* fc1_w  = (const float*)d_in[21];
    const float* fc1_b  = (const float*)d_in[22];
    const float* out_w  = (const float*)d_in[23];
    const float* out_b  = (const float*)d_in[24];
    float* out = (float*)d_out;

    float* xA   = (float*)d_ws;                          // N*F f32
    float* xB   = xA + (size_t)N_ATOMS * F;
    unsigned int* xPA = (unsigned int*)(xB + (size_t)N_ATOMS * F);
    unsigned int* xPB = xPA + (size_t)N_ATOMS * F;
    unsigned int* nbrP = xPB + (size_t)N_ATOMS * F;              // N*M*42, in-place
    float* pqbuf = (float*)(nbrP + (size_t)N_ATOMS * M * NBRS);  // N*1024
    float* sums = pqbuf + (size_t)N_ATOMS * PQW;                 // N0*F
    float* cnt  = sums + (size_t)N0 * F;
    float* sc1  = cnt + N0;                              // NC*K*D
    float* sh1  = sc1 + NCONV * K * D;
    float* sc2  = sh1 + NCONV * K * D;
    float* sh2  = sc2 + NCONV * K * F;
    unsigned short* wtpq = (unsigned short*)(sh2 + NCONV * K * F);  // NC*2*65536
    unsigned short* wtb  = wtpq + (size_t)NCONV * 2 * LFRAG_PQ;     // NC*2*32768

    prep_pq_kernel<<<(NCONV * LFRAG_PQ + 255) / 256, 256, 0, stream>>>(fc_w, wtpq);
    prep_bond_kernel<<<(NCONV * LFRAG_BD + 255) / 256, 256, 0, stream>>>(fc_w, wtb);
    prep2_kernel<<<(NCONV * K * D + 255) / 256, 256, 0, stream>>>(
        fc_b, bn1_g, bn1_b, bn1_m, bn1_v, bn2_g, bn2_b, bn2_m, bn2_v,
        sc1, sh1, sc2, sh2);
    npack_kernel<<<(N_ATOMS * M * NBRS + 255) / 256, 256, 0, stream>>>(nbr_fea, nbrP);
    emb_kernel<<<(N_ATOMS * F + 255) / 256, 256, 0, stream>>>(
        atom_fea, emb_w, emb_b, xA, xPA);

    // conv 0
    pq_kernel<<<N_ATOMS / 32, 512, 0, stream>>>(xPA, wtpq, pqbuf);
    conv_mfma<true><<<GRID, THREADS, 0, stream>>>(
        xA, nbrP, nbr_idx, wtb, pqbuf,
        sc1, sh1, sc2, sh2,
        atom_w, atom_b, nbr_w, nbr_b, xB, xPB);
    // conv 1
    pq_kernel<<<N_ATOMS / 32, 512, 0, stream>>>(xPB, wtpq + (size_t)2 * LFRAG_PQ, pqbuf);
    conv_mfma<true><<<GRID, THREADS, 0, stream>>>(
        xB, nbrP, nbr_idx, wtb + (size_t)2 * LFRAG_BD, pqbuf,
        sc1 + (size_t)1 * K * D, sh1 + (size_t)1 * K * D,
        sc2 + (size_t)1 * K * F, sh2 + (size_t)1 * K * F,
        atom_w + (size_t)1 * K * TWOK, atom_b + (size_t)1 * TWOK,
        nbr_w + (size_t)1 * K * TWOK, nbr_b + (size_t)1 * TWOK, xA, xPA);
    // conv 2 (last): new_nbr dead -> bond tiles skipped
    pq_kernel<<<N_ATOMS / 32, 512, 0, stream>>>(xPA, wtpq + (size_t)4 * LFRAG_PQ, pqbuf);
    conv_mfma<false><<<GRID, THREADS, 0, stream>>>(
        xA, nbrP, nbr_idx, wtb + (size_t)4 * LFRAG_BD, pqbuf,
        sc1 + (size_t)2 * K * D, sh1 + (size_t)2 * K * D,
        sc2 + (size_t)2 * K * F, sh2 + (size_t)2 * K * F,
        atom_w + (size_t)2 * K * TWOK, atom_b + (size_t)2 * TWOK,
        nbr_w + (size_t)2 * K * TWOK, nbr_b + (size_t)2 * TWOK, xB, xPB);

    hipMemsetAsync(sums, 0, (size_t)(N0 * F + N0) * sizeof(float), stream);
    pool_kernel<<<(N_ATOMS * F + 255) / 256, 256, 0, stream>>>(xB, cidx, sums, cnt);
    head_kernel<<<N0, H, 0, stream>>>(sums, cnt, fc1_w, fc1_b, out_w, out_b, out);
}